// Round 4
// baseline (221.895 us; speedup 1.0000x reference)
//
#include <hip/hip_runtime.h>

// out[b,d,n] = w[d] * in[b,d,n]; B=8, D=2048, N=2048, fp32.
// Streaming scale, roofline ~43 us at ~6.3-6.7 TB/s measured (harness fills).
// R4: 4 rows per block, 8 float4/thread (4096 blocks x 256 thr). All 8 loads
// issued before any store -> 8-deep MLP per lane to hide ~900-cyc HBM latency;
// weights remain block-uniform scalar loads. Nontemporal: pure streaming,
// 268 MB >> 32 MB L2.

typedef float floatx4 __attribute__((ext_vector_type(4)));

__global__ __launch_bounds__(256) void channel_scale_kernel(
    const floatx4* __restrict__ in, const float* __restrict__ w,
    floatx4* __restrict__ out) {
    const int b = blockIdx.x;              // handles rows [4b, 4b+4)
    const long base = (long)b * 2048;      // 4 rows * 512 float4s
    const int t = threadIdx.x;

    const float s0 = w[(4 * b + 0) & 2047];
    const float s1 = w[(4 * b + 1) & 2047];
    const float s2 = w[(4 * b + 2) & 2047];
    const float s3 = w[(4 * b + 3) & 2047];

    floatx4 v[8];
#pragma unroll
    for (int i = 0; i < 8; ++i)
        v[i] = __builtin_nontemporal_load(&in[base + i * 256 + t]);

    v[0] *= s0; v[1] *= s0;
    v[2] *= s1; v[3] *= s1;
    v[4] *= s2; v[5] *= s2;
    v[6] *= s3; v[7] *= s3;

#pragma unroll
    for (int i = 0; i < 8; ++i)
        __builtin_nontemporal_store(v[i], &out[base + i * 256 + t]);
}

extern "C" void kernel_launch(void* const* d_in, const int* in_sizes, int n_in,
                              void* d_out, int out_size, void* d_ws, size_t ws_size,
                              hipStream_t stream) {
    const floatx4* in = (const floatx4*)d_in[0];
    const float*   w  = (const float*)d_in[1];
    floatx4* out = (floatx4*)d_out;
    int blocks = out_size / 8192;          // (B*D)/4 = 4096 blocks
    channel_scale_kernel<<<blocks, 256, 0, stream>>>(in, w, out);
}